// Round 4
// baseline (190.886 us; speedup 1.0000x reference)
//
#include <hip/hip_runtime.h>

// x (32,256,56,56) f32, cols (64,4) i32. Per (b,g,w,h): among the 4 channels
// cols[g,:], keep only the FIRST max (jnp.argmax tie-break), zero the rest,
// then ReLU. cols covers all 256 channels, so every output elem is written.
constexpr int B  = 32;
constexpr int C  = 256;
constexpr int P  = 56 * 56;     // 3136 spatial elems per channel (contiguous)
constexpr int G  = 64;
constexpr int GS = 4;
constexpr int P8 = P / 8;       // 392 eight-float units per plane (32B aligned)
constexpr int TOTAL = B * G * P8;   // 802,816 threads (= 3136 * 256 exactly)
constexpr int BLOCK = 256;

typedef float fx4 __attribute__((ext_vector_type(4)));  // native vec: OK for nontemporal builtins

__global__ __launch_bounds__(BLOCK) void cgm_kernel(const float* __restrict__ x,
                                                    const int* __restrict__ cols,
                                                    float* __restrict__ out) {
    int tid = blockIdx.x * BLOCK + threadIdx.x;   // grid exact, no bounds check

    int u  = tid % P8;          // which 8-float chunk within the spatial plane
    int bg = tid / P8;
    int g  = bg & (G - 1);
    int b  = bg >> 6;

    long base_p = (long)u * 8;

    // Channel offsets for the 4 group slots (cols mostly wave-uniform).
    long off[GS];
#pragma unroll
    for (int s = 0; s < GS; ++s) {
        int c = cols[g * GS + s];
        off[s] = ((long)b * C + c) * P + base_p;
    }

    // 8 independent 16B loads issued up front -> 8 outstanding per wave (MLP).
    fx4 va[GS], vb[GS];
#pragma unroll
    for (int s = 0; s < GS; ++s) {
        const fx4* p = reinterpret_cast<const fx4*>(x + off[s]);
        va[s] = p[0];
        vb[s] = p[1];
    }

    // Unpack to [slot][component] for the 8 spatial positions.
    float v[GS][8];
#pragma unroll
    for (int s = 0; s < GS; ++s) {
#pragma unroll
        for (int j = 0; j < 4; ++j) {
            v[s][j]     = va[s][j];
            v[s][j + 4] = vb[s][j];
        }
    }

    float o[GS][8];
#pragma unroll
    for (int s = 0; s < GS; ++s)
#pragma unroll
        for (int j = 0; j < 8; ++j) o[s][j] = 0.0f;

    // Component-wise argmax with FIRST-max tie-break (strict >), then ReLU.
#pragma unroll
    for (int j = 0; j < 8; ++j) {
        int   bi   = 0;
        float best = v[0][j];
#pragma unroll
        for (int s = 1; s < GS; ++s) {
            if (v[s][j] > best) { best = v[s][j]; bi = s; }
        }
        float r = best > 0.0f ? best : 0.0f;
#pragma unroll
        for (int s = 0; s < GS; ++s) {
            if (s == bi) o[s][j] = r;
        }
    }

    // Nontemporal 16B stores (write-once output; keep L2 for input reads).
#pragma unroll
    for (int s = 0; s < GS; ++s) {
        fx4 oa, ob;
#pragma unroll
        for (int j = 0; j < 4; ++j) {
            oa[j] = o[s][j];
            ob[j] = o[s][j + 4];
        }
        fx4* p = reinterpret_cast<fx4*>(out + off[s]);
        __builtin_nontemporal_store(oa, p);
        __builtin_nontemporal_store(ob, p + 1);
    }
}

extern "C" void kernel_launch(void* const* d_in, const int* in_sizes, int n_in,
                              void* d_out, int out_size, void* d_ws, size_t ws_size,
                              hipStream_t stream) {
    const float* x    = (const float*)d_in[0];
    const int*   cols = (const int*)d_in[1];
    float*       out  = (float*)d_out;

    int blocks = TOTAL / BLOCK;   // 3136, exact
    cgm_kernel<<<dim3(blocks), dim3(BLOCK), 0, stream>>>(x, cols, out);
}

// Round 6
// 181.325 us; speedup vs baseline: 1.0527x; 1.0527x over previous
//
#include <hip/hip_runtime.h>

// x (32,256,56,56) f32, cols (64,4) i32. Per (b,g,w,h): among the 4 channels
// cols[g,:], keep only the FIRST max (jnp.argmax tie-break), zero the rest,
// then ReLU. cols covers all 256 channels, so every output elem is written.
constexpr int B  = 32;
constexpr int C  = 256;
constexpr int P  = 56 * 56;         // 3136 spatial elems per channel plane
constexpr int G  = 64;
constexpr int GS = 4;
constexpr int F  = P / 4;           // 784 float4 per plane
constexpr int TOTAL4 = B * G * F;   // 1,605,632 float4-tasks
constexpr int BLOCK = 256;
constexpr int PER_THREAD = 2;       // 2 tasks/thread -> 8 loads in flight
constexpr int BLOCKS = TOTAL4 / (BLOCK * PER_THREAD);   // 3136, exact

typedef float fx4 __attribute__((ext_vector_type(4)));

__global__ __launch_bounds__(BLOCK) void cgm_kernel(const float* __restrict__ x,
                                                    const int* __restrict__ cols,
                                                    float* __restrict__ out) {
    int t  = threadIdx.x;
    int k0 = blockIdx.x * (BLOCK * PER_THREAD) + t;   // grid exact, no bounds check

    // Addressing per task. Chunks are BLOCK-strided so every wave-level
    // load/store instruction covers a contiguous 1KB (full cachelines).
    long off[PER_THREAD][GS];
#pragma unroll
    for (int i = 0; i < PER_THREAD; ++i) {
        int k  = k0 + i * BLOCK;
        int u  = k % F;             // float4 index within the plane
        int bg = k / F;
        int g  = bg & (G - 1);
        int b  = bg >> 6;
#pragma unroll
        for (int s = 0; s < GS; ++s) {
            int c = cols[g * GS + s];
            off[i][s] = ((long)b * C + c) * P + (long)u * 4;
        }
    }

    // Issue all 8 independent 16B loads before any compute (MLP).
    fx4 v[PER_THREAD][GS];
#pragma unroll
    for (int i = 0; i < PER_THREAD; ++i)
#pragma unroll
        for (int s = 0; s < GS; ++s)
            v[i][s] = *reinterpret_cast<const fx4*>(x + off[i][s]);

    // Prevent the scheduler from phase-splitting loads across the compute.
    __builtin_amdgcn_sched_barrier(0);

#pragma unroll
    for (int i = 0; i < PER_THREAD; ++i) {
        fx4 o[GS];
#pragma unroll
        for (int s = 0; s < GS; ++s) o[s] = (fx4)0.0f;

        // Component-wise argmax, FIRST-max tie-break (strict >), then ReLU.
#pragma unroll
        for (int j = 0; j < 4; ++j) {
            int   bi   = 0;
            float best = v[i][0][j];
#pragma unroll
            for (int s = 1; s < GS; ++s) {
                if (v[i][s][j] > best) { best = v[i][s][j]; bi = s; }
            }
            float r = best > 0.0f ? best : 0.0f;
#pragma unroll
            for (int s = 0; s < GS; ++s) {
                if (s == bi) o[s][j] = r;
            }
        }

        // 4 contiguous-1KB wave stores per task.
#pragma unroll
        for (int s = 0; s < GS; ++s)
            *reinterpret_cast<fx4*>(out + off[i][s]) = o[s];
    }
}

extern "C" void kernel_launch(void* const* d_in, const int* in_sizes, int n_in,
                              void* d_out, int out_size, void* d_ws, size_t ws_size,
                              hipStream_t stream) {
    const float* x    = (const float*)d_in[0];
    const int*   cols = (const int*)d_in[1];
    float*       out  = (float*)d_out;

    cgm_kernel<<<dim3(BLOCKS), dim3(BLOCK), 0, stream>>>(x, cols, out);
}